// Round 1
// baseline (1103.203 us; speedup 1.0000x reference)
//
#include <hip/hip_runtime.h>
#include <cmath>

// MHA fused forward, MI355X gfx950.
// Numerics: Q/K path needs ~fp32 accuracy (scores std ~784, softmax ~argmax).
// Use split-bf16 (hi/lo) 3-term MFMA for Q/K projections and QK^T.
// V / PV / O-proj are plain bf16 MFMA (incoherent error, well within 2% thresh).
// d_ws usage: 6 x 16MB = 96MB (Qhi,Qlo,Khi,Klo,V,O).

typedef __bf16 bf16_t;
typedef __bf16 bf16x8 __attribute__((ext_vector_type(8)));
typedef float f32x4 __attribute__((ext_vector_type(4)));

struct RopeTab { float inv[32]; };

#define BM 128
#define BN 128
#define BKK 32
constexpr int GK = 1024;

// MODE 0: QK split (3-term MFMA), epilogue RoPE + hi/lo bf16 out [B,H,S,D]
// MODE 1: V plain bf16, out bf16 [B,H,S,D]
// MODE 2: A is bf16 input, out fp32 row-major [M,N]
template<int MODE>
__global__ __launch_bounds__(256) void gemm_bt(
    const void* __restrict__ Aptr,
    const float* __restrict__ Wptr,
    const int* __restrict__ tokpos,
    RopeTab tab,
    void* __restrict__ out0,
    void* __restrict__ out1)
{
  extern __shared__ __align__(16) char smem_raw[];
  bf16_t* Ah = (bf16_t*)smem_raw;      // [BM][BKK]
  bf16_t* Bh = Ah + BM*BKK;
  bf16_t* Al = Bh + BN*BKK;            // MODE0 only
  bf16_t* Bl = Al + BM*BKK;

  const int tid = threadIdx.x;
  const int lane = tid & 63;
  const int wv = tid >> 6;
  const int wr = wv >> 1, wc = wv & 1;
  const int la = lane & 15, lb = lane >> 4;
  const int row0 = blockIdx.x * BM;
  const int col0 = blockIdx.y * BN;

  f32x4 acc[4][4] = {};

  const int srow = tid >> 2;           // 0..63
  const int scol = (tid & 3) * 8;      // 0,8,16,24

  for (int k0 = 0; k0 < GK; k0 += BKK) {
    __syncthreads();
    #pragma unroll
    for (int i = 0; i < 2; ++i) {
      const int r = srow + i*64;
      // ---- stage A tile ----
      if (MODE == 2) {
        const bf16_t* As = (const bf16_t*)Aptr + (size_t)(row0 + r)*GK + k0 + scol;
        *(bf16x8*)&Ah[r*BKK + scol] = *(const bf16x8*)As;
      } else {
        const float* As = (const float*)Aptr + (size_t)(row0 + r)*GK + k0 + scol;
        f32x4 u = *(const f32x4*)As;
        f32x4 v = *(const f32x4*)(As + 4);
        bf16x8 h, l;
        #pragma unroll
        for (int jj = 0; jj < 4; ++jj) {
          bf16_t hb = (bf16_t)u[jj]; h[jj] = hb;
          if (MODE == 0) l[jj] = (bf16_t)(u[jj] - (float)hb);
          bf16_t hb2 = (bf16_t)v[jj]; h[4+jj] = hb2;
          if (MODE == 0) l[4+jj] = (bf16_t)(v[jj] - (float)hb2);
        }
        *(bf16x8*)&Ah[r*BKK + scol] = h;
        if (MODE == 0) *(bf16x8*)&Al[r*BKK + scol] = l;
      }
      // ---- stage W tile (always fp32 source, rows = N dim) ----
      {
        const float* Ws = Wptr + (size_t)(col0 + r)*GK + k0 + scol;
        f32x4 u = *(const f32x4*)Ws;
        f32x4 v = *(const f32x4*)(Ws + 4);
        bf16x8 h, l;
        #pragma unroll
        for (int jj = 0; jj < 4; ++jj) {
          bf16_t hb = (bf16_t)u[jj]; h[jj] = hb;
          if (MODE == 0) l[jj] = (bf16_t)(u[jj] - (float)hb);
          bf16_t hb2 = (bf16_t)v[jj]; h[4+jj] = hb2;
          if (MODE == 0) l[4+jj] = (bf16_t)(v[jj] - (float)hb2);
        }
        *(bf16x8*)&Bh[r*BKK + scol] = h;
        if (MODE == 0) *(bf16x8*)&Bl[r*BKK + scol] = l;
      }
    }
    __syncthreads();

    bf16x8 ah[4], al[4];
    #pragma unroll
    for (int m = 0; m < 4; ++m) {
      const int rr = (wr*64 + m*16 + la)*BKK + lb*8;
      ah[m] = *(const bf16x8*)&Ah[rr];
      if (MODE == 0) al[m] = *(const bf16x8*)&Al[rr];
    }
    #pragma unroll
    for (int n = 0; n < 4; ++n) {
      const int rr = (wc*64 + n*16 + la)*BKK + lb*8;
      const bf16x8 bh_ = *(const bf16x8*)&Bh[rr];
      #pragma unroll
      for (int m = 0; m < 4; ++m)
        acc[m][n] = __builtin_amdgcn_mfma_f32_16x16x32_bf16(ah[m], bh_, acc[m][n], 0, 0, 0);
      if (MODE == 0) {
        const bf16x8 bl_ = *(const bf16x8*)&Bl[rr];
        #pragma unroll
        for (int m = 0; m < 4; ++m) {
          acc[m][n] = __builtin_amdgcn_mfma_f32_16x16x32_bf16(al[m], bh_, acc[m][n], 0, 0, 0);
          acc[m][n] = __builtin_amdgcn_mfma_f32_16x16x32_bf16(ah[m], bl_, acc[m][n], 0, 0, 0);
        }
      }
    }
  }

  // ---- epilogue ----
  #pragma unroll
  for (int n = 0; n < 4; ++n) {
    const int gn = col0 + wc*64 + n*16 + la;
    #pragma unroll
    for (int m = 0; m < 4; ++m) {
      const int gm0 = row0 + wr*64 + m*16 + lb*4;
      if (MODE == 2) {
        float* O = (float*)out0;
        #pragma unroll
        for (int j = 0; j < 4; ++j)
          O[(size_t)(gm0 + j)*1024 + gn] = acc[m][n][j];
      } else if (MODE == 1) {
        bf16_t* O = (bf16_t*)out0;
        #pragma unroll
        for (int j = 0; j < 4; ++j) {
          const int gm = gm0 + j;
          const int b = gm >> 11, s = gm & 2047;
          const int h = gn >> 6, d = gn & 63;
          O[(((size_t)b*16 + h)*2048 + s)*64 + d] = (bf16_t)acc[m][n][j];
        }
      } else {
        const int d = gn & 63, h = gn >> 6;
        const bool odd = d & 1;
        const float inv = tab.inv[d >> 1];
        bf16_t* Oh = (bf16_t*)out0;
        bf16_t* Ol = (bf16_t*)out1;
        #pragma unroll
        for (int j = 0; j < 4; ++j) {
          const int gm = gm0 + j;
          const float t = acc[m][n][j];
          const float other = __shfl_xor(t, 1, 64);   // partner column d^1
          const int pos = tokpos[gm];
          float sn, cs;
          sincosf((float)pos * inv, &sn, &cs);
          const float r = odd ? (other*sn + t*cs) : (t*cs - other*sn);
          const bf16_t hb = (bf16_t)r;
          const int b = gm >> 11, s = gm & 2047;
          const size_t oi = (((size_t)b*16 + h)*2048 + s)*64 + d;
          Oh[oi] = hb;
          Ol[oi] = (bf16_t)(r - (float)hb);
        }
      }
    }
  }
}

// Flash attention, causal, split-bf16 QK^T. Grid (S/64, B*H), 4 waves/block.
__global__ __launch_bounds__(256) void attn_kernel(
    const bf16_t* __restrict__ Qhi, const bf16_t* __restrict__ Qlo,
    const bf16_t* __restrict__ Khi, const bf16_t* __restrict__ Klo,
    const bf16_t* __restrict__ Vb, bf16_t* __restrict__ O)
{
  __shared__ __align__(16) bf16_t sKh[64*64];
  __shared__ __align__(16) bf16_t sKl[64*64];
  __shared__ __align__(16) bf16_t sVt[64*64];   // transposed [d][kv]
  __shared__ __align__(16) bf16_t sP[4][16*64]; // per-wave P tile

  const int qb = blockIdx.x;
  const int bh = blockIdx.y;
  const int b = bh >> 4, h = bh & 15;
  const size_t base = (size_t)bh * 2048 * 64;
  const bf16_t* Qh_ = Qhi + base;
  const bf16_t* Ql_ = Qlo + base;
  const bf16_t* Kh_ = Khi + base;
  const bf16_t* Kl_ = Klo + base;
  const bf16_t* V_  = Vb  + base;

  const int tid = threadIdx.x, wv = tid >> 6, lane = tid & 63;
  const int la = lane & 15, lb = lane >> 4;

  const int qrow = qb*64 + wv*16 + la;
  bf16x8 qh[2], ql[2];
  #pragma unroll
  for (int kf = 0; kf < 2; ++kf) {
    qh[kf] = *(const bf16x8*)&Qh_[(size_t)qrow*64 + kf*32 + lb*8];
    ql[kf] = *(const bf16x8*)&Ql_[(size_t)qrow*64 + kf*32 + lb*8];
  }

  f32x4 oacc[4] = {};
  float mrow[4], lrow[4];
  #pragma unroll
  for (int j = 0; j < 4; ++j) { mrow[j] = -1e30f; lrow[j] = 0.f; }

  for (int kvb = 0; kvb <= qb; ++kvb) {
    const int kv0 = kvb * 64;
    __syncthreads();
    #pragma unroll
    for (int i = 0; i < 2; ++i) {
      const int e = (i*256 + tid) * 8;
      *(bf16x8*)&sKh[e] = *(const bf16x8*)&Kh_[(size_t)kv0*64 + e];
      *(bf16x8*)&sKl[e] = *(const bf16x8*)&Kl_[(size_t)kv0*64 + e];
      const bf16x8 vv = *(const bf16x8*)&V_[(size_t)kv0*64 + e];
      const int r = e >> 6, c = e & 63;
      #pragma unroll
      for (int jj = 0; jj < 8; ++jj) sVt[(c + jj)*64 + r] = vv[jj];
    }
    __syncthreads();

    // S = Q K^T (3-term split), S-frag: row(q)=lb*4+j, col(kv)=nf*16+la
    f32x4 sacc[4] = {};
    #pragma unroll
    for (int nf = 0; nf < 4; ++nf) {
      #pragma unroll
      for (int kf = 0; kf < 2; ++kf) {
        const int rr = (nf*16 + la)*64 + kf*32 + lb*8;
        const bf16x8 kh = *(const bf16x8*)&sKh[rr];
        const bf16x8 kl = *(const bf16x8*)&sKl[rr];
        sacc[nf] = __builtin_amdgcn_mfma_f32_16x16x32_bf16(qh[kf], kh, sacc[nf], 0, 0, 0);
        sacc[nf] = __builtin_amdgcn_mfma_f32_16x16x32_bf16(qh[kf], kl, sacc[nf], 0, 0, 0);
        sacc[nf] = __builtin_amdgcn_mfma_f32_16x16x32_bf16(ql[kf], kh, sacc[nf], 0, 0, 0);
      }
    }

    const int q0 = qb*64 + wv*16 + lb*4;
    if (kvb == qb) {
      #pragma unroll
      for (int nf = 0; nf < 4; ++nf)
        #pragma unroll
        for (int j = 0; j < 4; ++j) {
          const int kvi = kv0 + nf*16 + la;
          sacc[nf][j] = (kvi <= q0 + j) ? sacc[nf][j]*0.125f : -1e30f;
        }
    } else {
      #pragma unroll
      for (int nf = 0; nf < 4; ++nf)
        #pragma unroll
        for (int j = 0; j < 4; ++j) sacc[nf][j] *= 0.125f;
    }

    // row max over 64 cols: local then 16-lane butterfly
    f32x4 red;
    #pragma unroll
    for (int j = 0; j < 4; ++j)
      red[j] = fmaxf(fmaxf(sacc[0][j], sacc[1][j]), fmaxf(sacc[2][j], sacc[3][j]));
    #pragma unroll
    for (int off = 1; off < 16; off <<= 1)
      #pragma unroll
      for (int j = 0; j < 4; ++j)
        red[j] = fmaxf(red[j], __shfl_xor(red[j], off, 64));

    float sf[4];
    #pragma unroll
    for (int j = 0; j < 4; ++j) {
      const float mn = fmaxf(mrow[j], red[j]);
      sf[j] = __expf(mrow[j] - mn);
      mrow[j] = mn;
    }
    f32x4 rs = {};
    #pragma unroll
    for (int nf = 0; nf < 4; ++nf)
      #pragma unroll
      for (int j = 0; j < 4; ++j) {
        const float p = __expf(sacc[nf][j] - mrow[j]);
        sacc[nf][j] = p;
        rs[j] += p;
      }
    #pragma unroll
    for (int off = 1; off < 16; off <<= 1)
      #pragma unroll
      for (int j = 0; j < 4; ++j)
        rs[j] += __shfl_xor(rs[j], off, 64);
    #pragma unroll
    for (int j = 0; j < 4; ++j) lrow[j] = lrow[j]*sf[j] + rs[j];
    #pragma unroll
    for (int nf = 0; nf < 4; ++nf)
      #pragma unroll
      for (int j = 0; j < 4; ++j) oacc[nf][j] *= sf[j];

    // P -> LDS (bf16), per-wave region; same-wave RAW ordered by lgkmcnt
    #pragma unroll
    for (int nf = 0; nf < 4; ++nf)
      #pragma unroll
      for (int j = 0; j < 4; ++j)
        sP[wv][(lb*4 + j)*64 + nf*16 + la] = (bf16_t)sacc[nf][j];

    // O += P V
    #pragma unroll
    for (int ks = 0; ks < 2; ++ks) {
      const bf16x8 pa = *(const bf16x8*)&sP[wv][la*64 + ks*32 + lb*8];
      #pragma unroll
      for (int nf = 0; nf < 4; ++nf) {
        const bf16x8 vb2 = *(const bf16x8*)&sVt[(nf*16 + la)*64 + ks*32 + lb*8];
        oacc[nf] = __builtin_amdgcn_mfma_f32_16x16x32_bf16(pa, vb2, oacc[nf], 0, 0, 0);
      }
    }
  }

  // epilogue: O[b,s,h,d] bf16
  #pragma unroll
  for (int nf = 0; nf < 4; ++nf) {
    const int d = nf*16 + la;
    #pragma unroll
    for (int j = 0; j < 4; ++j) {
      const int s = qb*64 + wv*16 + lb*4 + j;
      const float val = oacc[nf][j] / lrow[j];
      O[(((size_t)b*2048 + s)*16 + h)*64 + d] = (bf16_t)val;
    }
  }
}

extern "C" void kernel_launch(void* const* d_in, const int* in_sizes, int n_in,
                              void* d_out, int out_size, void* d_ws, size_t ws_size,
                              hipStream_t stream)
{
  const float* x      = (const float*)d_in[0];
  const int*   tokpos = (const int*)d_in[1];
  const float* qw     = (const float*)d_in[2];
  const float* kw     = (const float*)d_in[3];
  const float* vw     = (const float*)d_in[4];
  const float* ow     = (const float*)d_in[5];
  float* out = (float*)d_out;

  const size_t E = (size_t)4*16*2048*64;  // 8388608 elems per tensor
  bf16_t* Qhi = (bf16_t*)d_ws;
  bf16_t* Qlo = Qhi + E;
  bf16_t* Khi = Qlo + E;
  bf16_t* Klo = Khi + E;
  bf16_t* V   = Klo + E;
  bf16_t* O   = V   + E;   // [B,S,H,D] = flat [8192,1024]

  RopeTab tab;
  for (int i = 0; i < 32; ++i)
    tab.inv[i] = (float)pow(10000.0, -(double)i / 32.0);

  dim3 grid(64, 8), blk(256);
  gemm_bt<0><<<grid, blk, 32768, stream>>>(x, qw, tokpos, tab, Qhi, Qlo);
  gemm_bt<0><<<grid, blk, 32768, stream>>>(x, kw, tokpos, tab, Khi, Klo);
  gemm_bt<1><<<grid, blk, 16384, stream>>>(x, vw, tokpos, tab, V, nullptr);
  attn_kernel<<<dim3(32, 64), blk, 0, stream>>>(Qhi, Qlo, Khi, Klo, V, O);
  gemm_bt<2><<<grid, blk, 16384, stream>>>(O, ow, tokpos, tab, out, nullptr);
}

// Round 2
// 922.491 us; speedup vs baseline: 1.1959x; 1.1959x over previous
//
#include <hip/hip_runtime.h>
#include <cmath>

// MHA fused forward, MI355X gfx950.
// R1: attn LDS XOR-swizzle (T2), V stored pre-transposed [b,h,d,s],
//     longest-first qb order, setprio around MFMA clusters.
// Numerics: split-bf16 (hi/lo) 3-term MFMA for Q/K projections and QK^T.
// d_ws usage: 6 x 16MB = 96MB (Qhi,Qlo,Khi,Klo,Vt,O).

typedef __bf16 bf16_t;
typedef __bf16 bf16x8 __attribute__((ext_vector_type(8)));
typedef float f32x4 __attribute__((ext_vector_type(4)));

struct RopeTab { float inv[32]; };

#define BM 128
#define BN 128
#define BKK 32
constexpr int GK = 1024;

// XOR swizzle for 64-elem-wide bf16 LDS tiles (row = 128B):
// spreads column-slot reads across 8 bank groups. Bijective per row.
__device__ __forceinline__ int SW(int e) { return e ^ (((e >> 6) & 7) << 3); }

// MODE 0: QK split (3-term MFMA), epilogue RoPE + hi/lo bf16 out [B,H,S,D]
// MODE 1: V plain bf16, out bf16 TRANSPOSED [B,H,D,S]
// MODE 2: A is bf16 input, out fp32 row-major [M,N]
template<int MODE>
__global__ __launch_bounds__(256) void gemm_bt(
    const void* __restrict__ Aptr,
    const float* __restrict__ Wptr,
    const int* __restrict__ tokpos,
    RopeTab tab,
    void* __restrict__ out0,
    void* __restrict__ out1)
{
  extern __shared__ __align__(16) char smem_raw[];
  bf16_t* Ah = (bf16_t*)smem_raw;      // [BM][BKK]
  bf16_t* Bh = Ah + BM*BKK;
  bf16_t* Al = Bh + BN*BKK;            // MODE0 only
  bf16_t* Bl = Al + BM*BKK;

  const int tid = threadIdx.x;
  const int lane = tid & 63;
  const int wv = tid >> 6;
  const int wr = wv >> 1, wc = wv & 1;
  const int la = lane & 15, lb = lane >> 4;
  const int row0 = blockIdx.x * BM;
  const int col0 = blockIdx.y * BN;

  f32x4 acc[4][4] = {};

  const int srow = tid >> 2;           // 0..63
  const int scol = (tid & 3) * 8;      // 0,8,16,24

  for (int k0 = 0; k0 < GK; k0 += BKK) {
    __syncthreads();
    #pragma unroll
    for (int i = 0; i < 2; ++i) {
      const int r = srow + i*64;
      // ---- stage A tile ----
      if (MODE == 2) {
        const bf16_t* As = (const bf16_t*)Aptr + (size_t)(row0 + r)*GK + k0 + scol;
        *(bf16x8*)&Ah[r*BKK + scol] = *(const bf16x8*)As;
      } else {
        const float* As = (const float*)Aptr + (size_t)(row0 + r)*GK + k0 + scol;
        f32x4 u = *(const f32x4*)As;
        f32x4 v = *(const f32x4*)(As + 4);
        bf16x8 h, l;
        #pragma unroll
        for (int jj = 0; jj < 4; ++jj) {
          bf16_t hb = (bf16_t)u[jj]; h[jj] = hb;
          if (MODE == 0) l[jj] = (bf16_t)(u[jj] - (float)hb);
          bf16_t hb2 = (bf16_t)v[jj]; h[4+jj] = hb2;
          if (MODE == 0) l[4+jj] = (bf16_t)(v[jj] - (float)hb2);
        }
        *(bf16x8*)&Ah[r*BKK + scol] = h;
        if (MODE == 0) *(bf16x8*)&Al[r*BKK + scol] = l;
      }
      // ---- stage W tile (always fp32 source, rows = N dim) ----
      {
        const float* Ws = Wptr + (size_t)(col0 + r)*GK + k0 + scol;
        f32x4 u = *(const f32x4*)Ws;
        f32x4 v = *(const f32x4*)(Ws + 4);
        bf16x8 h, l;
        #pragma unroll
        for (int jj = 0; jj < 4; ++jj) {
          bf16_t hb = (bf16_t)u[jj]; h[jj] = hb;
          if (MODE == 0) l[jj] = (bf16_t)(u[jj] - (float)hb);
          bf16_t hb2 = (bf16_t)v[jj]; h[4+jj] = hb2;
          if (MODE == 0) l[4+jj] = (bf16_t)(v[jj] - (float)hb2);
        }
        *(bf16x8*)&Bh[r*BKK + scol] = h;
        if (MODE == 0) *(bf16x8*)&Bl[r*BKK + scol] = l;
      }
    }
    __syncthreads();

    bf16x8 ah[4], al[4];
    #pragma unroll
    for (int m = 0; m < 4; ++m) {
      const int rr = (wr*64 + m*16 + la)*BKK + lb*8;
      ah[m] = *(const bf16x8*)&Ah[rr];
      if (MODE == 0) al[m] = *(const bf16x8*)&Al[rr];
    }
    #pragma unroll
    for (int n = 0; n < 4; ++n) {
      const int rr = (wc*64 + n*16 + la)*BKK + lb*8;
      const bf16x8 bh_ = *(const bf16x8*)&Bh[rr];
      #pragma unroll
      for (int m = 0; m < 4; ++m)
        acc[m][n] = __builtin_amdgcn_mfma_f32_16x16x32_bf16(ah[m], bh_, acc[m][n], 0, 0, 0);
      if (MODE == 0) {
        const bf16x8 bl_ = *(const bf16x8*)&Bl[rr];
        #pragma unroll
        for (int m = 0; m < 4; ++m) {
          acc[m][n] = __builtin_amdgcn_mfma_f32_16x16x32_bf16(al[m], bh_, acc[m][n], 0, 0, 0);
          acc[m][n] = __builtin_amdgcn_mfma_f32_16x16x32_bf16(ah[m], bl_, acc[m][n], 0, 0, 0);
        }
      }
    }
  }

  // ---- epilogue ----
  #pragma unroll
  for (int n = 0; n < 4; ++n) {
    const int gn = col0 + wc*64 + n*16 + la;
    #pragma unroll
    for (int m = 0; m < 4; ++m) {
      const int gm0 = row0 + wr*64 + m*16 + lb*4;
      if (MODE == 2) {
        float* O = (float*)out0;
        #pragma unroll
        for (int j = 0; j < 4; ++j)
          O[(size_t)(gm0 + j)*1024 + gn] = acc[m][n][j];
      } else if (MODE == 1) {
        // V^T layout: [B,H,D,S]
        bf16_t* O = (bf16_t*)out0;
        #pragma unroll
        for (int j = 0; j < 4; ++j) {
          const int gm = gm0 + j;
          const int b = gm >> 11, s = gm & 2047;
          const int h = gn >> 6, d = gn & 63;
          O[(((size_t)b*16 + h)*64 + d)*2048 + s] = (bf16_t)acc[m][n][j];
        }
      } else {
        const int d = gn & 63, h = gn >> 6;
        const bool odd = d & 1;
        const float inv = tab.inv[d >> 1];
        bf16_t* Oh = (bf16_t*)out0;
        bf16_t* Ol = (bf16_t*)out1;
        #pragma unroll
        for (int j = 0; j < 4; ++j) {
          const int gm = gm0 + j;
          const float t = acc[m][n][j];
          const float other = __shfl_xor(t, 1, 64);   // partner column d^1
          const int pos = tokpos[gm];
          float sn, cs;
          sincosf((float)pos * inv, &sn, &cs);
          const float r = odd ? (other*sn + t*cs) : (t*cs - other*sn);
          const bf16_t hb = (bf16_t)r;
          const int b = gm >> 11, s = gm & 2047;
          const size_t oi = (((size_t)b*16 + h)*2048 + s)*64 + d;
          Oh[oi] = hb;
          Ol[oi] = (bf16_t)(r - (float)hb);
        }
      }
    }
  }
}

// Flash attention, causal, split-bf16 QK^T. Grid (S/64, B*H), 4 waves/block.
// V input is pre-transposed [B,H,D,S]. All LDS accesses XOR-swizzled.
__global__ __launch_bounds__(256) void attn_kernel(
    const bf16_t* __restrict__ Qhi, const bf16_t* __restrict__ Qlo,
    const bf16_t* __restrict__ Khi, const bf16_t* __restrict__ Klo,
    const bf16_t* __restrict__ Vt, bf16_t* __restrict__ O)
{
  __shared__ __align__(16) bf16_t sKh[64*64];
  __shared__ __align__(16) bf16_t sKl[64*64];
  __shared__ __align__(16) bf16_t sVt[64*64];   // [d][kv]
  __shared__ __align__(16) bf16_t sP[4*16*64];  // per-wave P tile

  const int qb = (int)gridDim.x - 1 - (int)blockIdx.x;  // longest-first
  const int bh = blockIdx.y;
  const int b = bh >> 4, h = bh & 15;
  const size_t base = (size_t)bh * 2048 * 64;
  const bf16_t* Qh_ = Qhi + base;
  const bf16_t* Ql_ = Qlo + base;
  const bf16_t* Kh_ = Khi + base;
  const bf16_t* Kl_ = Klo + base;
  const bf16_t* Vt_ = Vt  + base;    // [64 d][2048 s]

  const int tid = threadIdx.x, wv = tid >> 6, lane = tid & 63;
  const int la = lane & 15, lb = lane >> 4;

  const int qrow = qb*64 + wv*16 + la;
  bf16x8 qh[2], ql[2];
  #pragma unroll
  for (int kf = 0; kf < 2; ++kf) {
    qh[kf] = *(const bf16x8*)&Qh_[(size_t)qrow*64 + kf*32 + lb*8];
    ql[kf] = *(const bf16x8*)&Ql_[(size_t)qrow*64 + kf*32 + lb*8];
  }

  f32x4 oacc[4] = {};
  float mrow[4], lrow[4];
  #pragma unroll
  for (int j = 0; j < 4; ++j) { mrow[j] = -1e30f; lrow[j] = 0.f; }

  for (int kvb = 0; kvb <= qb; ++kvb) {
    const int kv0 = kvb * 64;
    __syncthreads();
    #pragma unroll
    for (int i = 0; i < 2; ++i) {
      const int e = (i*256 + tid) * 8;         // linear elem idx in 64x64 tile
      const int ed = SW(e);                    // swizzled dest (16B aligned)
      *(bf16x8*)&sKh[ed] = *(const bf16x8*)&Kh_[(size_t)kv0*64 + e];
      *(bf16x8*)&sKl[ed] = *(const bf16x8*)&Kl_[(size_t)kv0*64 + e];
      const int r = e >> 6, c = e & 63;        // V^T: row=d, col=kv
      *(bf16x8*)&sVt[ed] = *(const bf16x8*)&Vt_[(size_t)r*2048 + kv0 + c];
    }
    __syncthreads();

    // S = Q K^T (3-term split), S-frag: row(q)=lb*4+j, col(kv)=nf*16+la
    f32x4 sacc[4] = {};
    __builtin_amdgcn_s_setprio(1);
    #pragma unroll
    for (int nf = 0; nf < 4; ++nf) {
      #pragma unroll
      for (int kf = 0; kf < 2; ++kf) {
        const int rr = SW((nf*16 + la)*64 + kf*32 + lb*8);
        const bf16x8 kh = *(const bf16x8*)&sKh[rr];
        const bf16x8 kl = *(const bf16x8*)&sKl[rr];
        sacc[nf] = __builtin_amdgcn_mfma_f32_16x16x32_bf16(qh[kf], kh, sacc[nf], 0, 0, 0);
        sacc[nf] = __builtin_amdgcn_mfma_f32_16x16x32_bf16(qh[kf], kl, sacc[nf], 0, 0, 0);
        sacc[nf] = __builtin_amdgcn_mfma_f32_16x16x32_bf16(ql[kf], kh, sacc[nf], 0, 0, 0);
      }
    }
    __builtin_amdgcn_s_setprio(0);

    const int q0 = qb*64 + wv*16 + lb*4;
    if (kvb == qb) {
      #pragma unroll
      for (int nf = 0; nf < 4; ++nf)
        #pragma unroll
        for (int j = 0; j < 4; ++j) {
          const int kvi = kv0 + nf*16 + la;
          sacc[nf][j] = (kvi <= q0 + j) ? sacc[nf][j]*0.125f : -1e30f;
        }
    } else {
      #pragma unroll
      for (int nf = 0; nf < 4; ++nf)
        #pragma unroll
        for (int j = 0; j < 4; ++j) sacc[nf][j] *= 0.125f;
    }

    // row max over 64 cols: local then 16-lane butterfly
    f32x4 red;
    #pragma unroll
    for (int j = 0; j < 4; ++j)
      red[j] = fmaxf(fmaxf(sacc[0][j], sacc[1][j]), fmaxf(sacc[2][j], sacc[3][j]));
    #pragma unroll
    for (int off = 1; off < 16; off <<= 1)
      #pragma unroll
      for (int j = 0; j < 4; ++j)
        red[j] = fmaxf(red[j], __shfl_xor(red[j], off, 64));

    float sf[4];
    #pragma unroll
    for (int j = 0; j < 4; ++j) {
      const float mn = fmaxf(mrow[j], red[j]);
      sf[j] = __expf(mrow[j] - mn);
      mrow[j] = mn;
    }
    f32x4 rs = {};
    #pragma unroll
    for (int nf = 0; nf < 4; ++nf)
      #pragma unroll
      for (int j = 0; j < 4; ++j) {
        const float p = __expf(sacc[nf][j] - mrow[j]);
        sacc[nf][j] = p;
        rs[j] += p;
      }
    #pragma unroll
    for (int off = 1; off < 16; off <<= 1)
      #pragma unroll
      for (int j = 0; j < 4; ++j)
        rs[j] += __shfl_xor(rs[j], off, 64);
    #pragma unroll
    for (int j = 0; j < 4; ++j) lrow[j] = lrow[j]*sf[j] + rs[j];
    #pragma unroll
    for (int nf = 0; nf < 4; ++nf)
      #pragma unroll
      for (int j = 0; j < 4; ++j) oacc[nf][j] *= sf[j];

    // P -> LDS (bf16), per-wave region; same-wave RAW ordered by lgkmcnt
    #pragma unroll
    for (int nf = 0; nf < 4; ++nf)
      #pragma unroll
      for (int j = 0; j < 4; ++j)
        sP[SW(wv*1024 + (lb*4 + j)*64 + nf*16 + la)] = (bf16_t)sacc[nf][j];

    // O += P V
    __builtin_amdgcn_s_setprio(1);
    #pragma unroll
    for (int ks = 0; ks < 2; ++ks) {
      const bf16x8 pa = *(const bf16x8*)&sP[SW(wv*1024 + la*64 + ks*32 + lb*8)];
      #pragma unroll
      for (int nf = 0; nf < 4; ++nf) {
        const bf16x8 vb2 = *(const bf16x8*)&sVt[SW((nf*16 + la)*64 + ks*32 + lb*8)];
        oacc[nf] = __builtin_amdgcn_mfma_f32_16x16x32_bf16(pa, vb2, oacc[nf], 0, 0, 0);
      }
    }
    __builtin_amdgcn_s_setprio(0);
  }

  // epilogue: O[b,s,h,d] bf16
  #pragma unroll
  for (int nf = 0; nf < 4; ++nf) {
    const int d = nf*16 + la;
    #pragma unroll
    for (int j = 0; j < 4; ++j) {
      const int s = qb*64 + wv*16 + lb*4 + j;
      const float val = oacc[nf][j] / lrow[j];
      O[(((size_t)b*2048 + s)*16 + h)*64 + d] = (bf16_t)val;
    }
  }
}

extern "C" void kernel_launch(void* const* d_in, const int* in_sizes, int n_in,
                              void* d_out, int out_size, void* d_ws, size_t ws_size,
                              hipStream_t stream)
{
  const float* x      = (const float*)d_in[0];
  const int*   tokpos = (const int*)d_in[1];
  const float* qw     = (const float*)d_in[2];
  const float* kw     = (const float*)d_in[3];
  const float* vw     = (const float*)d_in[4];
  const float* ow     = (const float*)d_in[5];
  float* out = (float*)d_out;

  const size_t E = (size_t)4*16*2048*64;  // 8388608 elems per tensor
  bf16_t* Qhi = (bf16_t*)d_ws;
  bf16_t* Qlo = Qhi + E;
  bf16_t* Khi = Qlo + E;
  bf16_t* Klo = Khi + E;
  bf16_t* Vt  = Klo + E;   // [B,H,D,S]
  bf16_t* O   = Vt  + E;   // [B,S,H,D] = flat [8192,1024]

  RopeTab tab;
  for (int i = 0; i < 32; ++i)
    tab.inv[i] = (float)pow(10000.0, -(double)i / 32.0);

  dim3 grid(64, 8), blk(256);
  gemm_bt<0><<<grid, blk, 32768, stream>>>(x, qw, tokpos, tab, Qhi, Qlo);
  gemm_bt<0><<<grid, blk, 32768, stream>>>(x, kw, tokpos, tab, Khi, Klo);
  gemm_bt<1><<<grid, blk, 16384, stream>>>(x, vw, tokpos, tab, Vt, nullptr);
  attn_kernel<<<dim3(32, 64), blk, 0, stream>>>(Qhi, Qlo, Khi, Klo, Vt, O);
  gemm_bt<2><<<grid, blk, 16384, stream>>>(O, ow, tokpos, tab, out, nullptr);
}

// Round 3
// 476.405 us; speedup vs baseline: 2.3157x; 1.9364x over previous
//
#include <hip/hip_runtime.h>
#include <cmath>

// MHA fused forward, MI355X gfx950.
// R2: projection GEMMs rebuilt on the m97 structure:
//   - fp32->bf16 hi/lo split hoisted to pre-passes (x, weights)
//   - 3-term split GEMM = one bf16 GEMM with K_eff=3072 (segment pointer select)
//   - global_load_lds width=16 staging, linear LDS dest + inverse-swizzled
//     global source + swizzled ds_read (rule #21) -> conflict-free
//   - Q and K merged into one launch (grid z=2), 1024 blocks
//   - RoPE cos/sin from a precomputed device table (no sincosf in epilogue)
// attn kernel unchanged from R1 (swizzled, V^T, longest-first, setprio).

typedef __bf16 bf16_t;
typedef __bf16 bf16x4 __attribute__((ext_vector_type(4)));
typedef __bf16 bf16x8 __attribute__((ext_vector_type(8)));
typedef float f32x2 __attribute__((ext_vector_type(2)));
typedef float f32x4 __attribute__((ext_vector_type(4)));
typedef unsigned int u32;
typedef const __attribute__((address_space(1))) u32* gaddr_t;
typedef __attribute__((address_space(3))) u32* saddr_t;

struct RopeTab { float inv[32]; };

// ---------------- pre-pass: fp32 -> bf16 hi (+lo) ----------------
template<bool LO>
__global__ __launch_bounds__(256) void split_k(const float* __restrict__ in,
                                               bf16_t* __restrict__ hi,
                                               bf16_t* __restrict__ lo)
{
  const int i = blockIdx.x * 256 + threadIdx.x;
  const f32x4 u = *(const f32x4*)(in + (size_t)i * 4);
  bf16x4 h, l;
  #pragma unroll
  for (int j = 0; j < 4; ++j) {
    const bf16_t hb = (bf16_t)u[j];
    h[j] = hb;
    if (LO) l[j] = (bf16_t)(u[j] - (float)hb);
  }
  *(bf16x4*)(hi + (size_t)i * 4) = h;
  if (LO) *(bf16x4*)(lo + (size_t)i * 4) = l;
}

// ---------------- pre-pass: RoPE cos/sin table [pos][32 pairs] ----------------
__global__ __launch_bounds__(256) void rope_tab_k(RopeTab tab, float* __restrict__ T)
{
  const int i = blockIdx.x * 256 + threadIdx.x;   // 2048*32 entries
  const int p = i >> 5, d2 = i & 31;
  float sn, cs;
  sincosf((float)p * tab.inv[d2], &sn, &cs);
  T[(size_t)i * 2]     = cs;
  T[(size_t)i * 2 + 1] = sn;
}

// ---------------- GEMM (B^T): out[m,n] = sum_k A[m,k] * W[n,k] ----------------
// MODE 0: A = Xh/Xl, W = Wh/Wl (z selects q/k weights), K_eff=3072 (3 segments:
//         hh, hl, lh). Epilogue: RoPE via table -> hi/lo bf16 out [B,H,S,D].
// MODE 1: plain bf16 K=1024, out bf16 transposed [B,H,D,S] (packed 8B stores).
// MODE 2: plain bf16 K=1024, out fp32 [M,N].
template<int MODE>
__global__ __launch_bounds__(256) void gemm_k(
    const bf16_t* __restrict__ Agh, const bf16_t* __restrict__ Agl,
    const bf16_t* __restrict__ W0h, const bf16_t* __restrict__ W0l,
    const bf16_t* __restrict__ W1h, const bf16_t* __restrict__ W1l,
    const int* __restrict__ tokpos, const float* __restrict__ ropeT,
    bf16_t* __restrict__ Oq_h, bf16_t* __restrict__ Oq_l,
    bf16_t* __restrict__ Ok_h, bf16_t* __restrict__ Ok_l,
    float* __restrict__ Of)
{
  __shared__ __align__(16) bf16_t sA[128 * 64];
  __shared__ __align__(16) bf16_t sB[128 * 64];

  const int tid = threadIdx.x;
  const int lane = tid & 63, wv = tid >> 6;
  const int wr = wv >> 1, wc = wv & 1;
  const int la = lane & 15, lb = lane >> 4;
  const int row0 = blockIdx.x * 128, col0 = blockIdx.y * 128;
  const int z = blockIdx.z;

  const bf16_t* Wh = z ? W1h : W0h;
  const bf16_t* Wl = z ? W1l : W0l;

  // staging geometry: wave wv covers tile rows [wv*32, wv*32+32)
  const int srow = wv * 32 + (lane >> 3);   // + i*8
  const int schk = lane & 7;                // physical 16B chunk within row

  f32x4 acc[4][4] = {};

  const int NSEG = (MODE == 0) ? 3 : 1;
  for (int seg = 0; seg < NSEG; ++seg) {
    const bf16_t* Ap = (MODE == 0 && seg == 2) ? Agl : Agh;
    const bf16_t* Wp = (MODE == 0 && seg == 1) ? Wl  : Wh;
    for (int k0 = 0; k0 < 1024; k0 += 64) {
      __syncthreads();
      #pragma unroll
      for (int i = 0; i < 4; ++i) {
        const int r = srow + i * 8;
        const int cs_ = ((schk ^ (r & 7)) * 8);          // inverse-swizzled source col
        __builtin_amdgcn_global_load_lds(
            (gaddr_t)(Ap + (size_t)(row0 + r) * 1024 + k0 + cs_),
            (saddr_t)(sA + wv * 2048 + i * 512), 16, 0, 0);
        __builtin_amdgcn_global_load_lds(
            (gaddr_t)(Wp + (size_t)(col0 + r) * 1024 + k0 + cs_),
            (saddr_t)(sB + wv * 2048 + i * 512), 16, 0, 0);
      }
      __syncthreads();

      #pragma unroll
      for (int ks = 0; ks < 2; ++ks) {
        bf16x8 af[4];
        #pragma unroll
        for (int m = 0; m < 4; ++m) {
          const int r = wr * 64 + m * 16 + la;
          af[m] = *(const bf16x8*)&sA[r * 64 + (((ks * 4 + lb) ^ (la & 7)) * 8)];
        }
        #pragma unroll
        for (int n = 0; n < 4; ++n) {
          const int r = wc * 64 + n * 16 + la;
          const bf16x8 bfr = *(const bf16x8*)&sB[r * 64 + (((ks * 4 + lb) ^ (la & 7)) * 8)];
          #pragma unroll
          for (int m = 0; m < 4; ++m)
            acc[m][n] = __builtin_amdgcn_mfma_f32_16x16x32_bf16(af[m], bfr, acc[m][n], 0, 0, 0);
        }
      }
    }
  }

  // ---- epilogue ----
  #pragma unroll
  for (int n = 0; n < 4; ++n) {
    const int gn = col0 + wc * 64 + n * 16 + la;
    #pragma unroll
    for (int m = 0; m < 4; ++m) {
      const int gm0 = row0 + wr * 64 + m * 16 + lb * 4;
      if (MODE == 2) {
        #pragma unroll
        for (int j = 0; j < 4; ++j)
          Of[(size_t)(gm0 + j) * 1024 + gn] = acc[m][n][j];
      } else if (MODE == 1) {
        const int b = gm0 >> 11, s0 = gm0 & 2047;
        const int h = gn >> 6, d = gn & 63;
        bf16x4 v;
        #pragma unroll
        for (int j = 0; j < 4; ++j) v[j] = (bf16_t)acc[m][n][j];
        *(bf16x4*)&Oq_h[(((size_t)b * 16 + h) * 64 + d) * 2048 + s0] = v;
      } else {
        const int d = gn & 63, h = gn >> 6;
        const bool odd = d & 1;
        bf16_t* Oh = z ? Ok_h : Oq_h;
        bf16_t* Ol = z ? Ok_l : Oq_l;
        #pragma unroll
        for (int j = 0; j < 4; ++j) {
          const int gm = gm0 + j;
          const float t = acc[m][n][j];
          const float other = __shfl_xor(t, 1, 64);   // partner column d^1
          const int pos = tokpos[gm];
          const f32x2 cs2 = *(const f32x2*)&ropeT[((size_t)pos << 6) + ((d >> 1) << 1)];
          const float r = odd ? (other * cs2[1] + t * cs2[0])
                              : (t * cs2[0] - other * cs2[1]);
          const bf16_t hb = (bf16_t)r;
          const int b = gm >> 11, s = gm & 2047;
          const size_t oi = (((size_t)b * 16 + h) * 2048 + s) * 64 + d;
          Oh[oi] = hb;
          Ol[oi] = (bf16_t)(r - (float)hb);
        }
      }
    }
  }
}

// XOR swizzle for 64-elem-wide bf16 LDS tiles (row = 128B) — attn kernel.
__device__ __forceinline__ int SW(int e) { return e ^ (((e >> 6) & 7) << 3); }

// Flash attention, causal, split-bf16 QK^T. Grid (S/64, B*H), 4 waves/block.
__global__ __launch_bounds__(256) void attn_kernel(
    const bf16_t* __restrict__ Qhi, const bf16_t* __restrict__ Qlo,
    const bf16_t* __restrict__ Khi, const bf16_t* __restrict__ Klo,
    const bf16_t* __restrict__ Vt, bf16_t* __restrict__ O)
{
  __shared__ __align__(16) bf16_t sKh[64 * 64];
  __shared__ __align__(16) bf16_t sKl[64 * 64];
  __shared__ __align__(16) bf16_t sVt[64 * 64];   // [d][kv]
  __shared__ __align__(16) bf16_t sP[4 * 16 * 64];

  const int qb = (int)gridDim.x - 1 - (int)blockIdx.x;  // longest-first
  const int bh = blockIdx.y;
  const int b = bh >> 4, h = bh & 15;
  const size_t base = (size_t)bh * 2048 * 64;
  const bf16_t* Qh_ = Qhi + base;
  const bf16_t* Ql_ = Qlo + base;
  const bf16_t* Kh_ = Khi + base;
  const bf16_t* Kl_ = Klo + base;
  const bf16_t* Vt_ = Vt + base;    // [64 d][2048 s]

  const int tid = threadIdx.x, wv = tid >> 6, lane = tid & 63;
  const int la = lane & 15, lb = lane >> 4;

  const int qrow = qb * 64 + wv * 16 + la;
  bf16x8 qh[2], ql[2];
  #pragma unroll
  for (int kf = 0; kf < 2; ++kf) {
    qh[kf] = *(const bf16x8*)&Qh_[(size_t)qrow * 64 + kf * 32 + lb * 8];
    ql[kf] = *(const bf16x8*)&Ql_[(size_t)qrow * 64 + kf * 32 + lb * 8];
  }

  f32x4 oacc[4] = {};
  float mrow[4], lrow[4];
  #pragma unroll
  for (int j = 0; j < 4; ++j) { mrow[j] = -1e30f; lrow[j] = 0.f; }

  for (int kvb = 0; kvb <= qb; ++kvb) {
    const int kv0 = kvb * 64;
    __syncthreads();
    #pragma unroll
    for (int i = 0; i < 2; ++i) {
      const int e = (i * 256 + tid) * 8;
      const int ed = SW(e);
      *(bf16x8*)&sKh[ed] = *(const bf16x8*)&Kh_[(size_t)kv0 * 64 + e];
      *(bf16x8*)&sKl[ed] = *(const bf16x8*)&Kl_[(size_t)kv0 * 64 + e];
      const int r = e >> 6, c = e & 63;
      *(bf16x8*)&sVt[ed] = *(const bf16x8*)&Vt_[(size_t)r * 2048 + kv0 + c];
    }
    __syncthreads();

    f32x4 sacc[4] = {};
    __builtin_amdgcn_s_setprio(1);
    #pragma unroll
    for (int nf = 0; nf < 4; ++nf) {
      #pragma unroll
      for (int kf = 0; kf < 2; ++kf) {
        const int rr = SW((nf * 16 + la) * 64 + kf * 32 + lb * 8);
        const bf16x8 kh = *(const bf16x8*)&sKh[rr];
        const bf16x8 kl = *(const bf16x8*)&sKl[rr];
        sacc[nf] = __builtin_amdgcn_mfma_f32_16x16x32_bf16(qh[kf], kh, sacc[nf], 0, 0, 0);
        sacc[nf] = __builtin_amdgcn_mfma_f32_16x16x32_bf16(qh[kf], kl, sacc[nf], 0, 0, 0);
        sacc[nf] = __builtin_amdgcn_mfma_f32_16x16x32_bf16(ql[kf], kh, sacc[nf], 0, 0, 0);
      }
    }
    __builtin_amdgcn_s_setprio(0);

    const int q0 = qb * 64 + wv * 16 + lb * 4;
    if (kvb == qb) {
      #pragma unroll
      for (int nf = 0; nf < 4; ++nf)
        #pragma unroll
        for (int j = 0; j < 4; ++j) {
          const int kvi = kv0 + nf * 16 + la;
          sacc[nf][j] = (kvi <= q0 + j) ? sacc[nf][j] * 0.125f : -1e30f;
        }
    } else {
      #pragma unroll
      for (int nf = 0; nf < 4; ++nf)
        #pragma unroll
        for (int j = 0; j < 4; ++j) sacc[nf][j] *= 0.125f;
    }

    f32x4 red;
    #pragma unroll
    for (int j = 0; j < 4; ++j)
      red[j] = fmaxf(fmaxf(sacc[0][j], sacc[1][j]), fmaxf(sacc[2][j], sacc[3][j]));
    #pragma unroll
    for (int off = 1; off < 16; off <<= 1)
      #pragma unroll
      for (int j = 0; j < 4; ++j)
        red[j] = fmaxf(red[j], __shfl_xor(red[j], off, 64));

    float sf[4];
    #pragma unroll
    for (int j = 0; j < 4; ++j) {
      const float mn = fmaxf(mrow[j], red[j]);
      sf[j] = __expf(mrow[j] - mn);
      mrow[j] = mn;
    }
    f32x4 rs = {};
    #pragma unroll
    for (int nf = 0; nf < 4; ++nf)
      #pragma unroll
      for (int j = 0; j < 4; ++j) {
        const float p = __expf(sacc[nf][j] - mrow[j]);
        sacc[nf][j] = p;
        rs[j] += p;
      }
    #pragma unroll
    for (int off = 1; off < 16; off <<= 1)
      #pragma unroll
      for (int j = 0; j < 4; ++j)
        rs[j] += __shfl_xor(rs[j], off, 64);
    #pragma unroll
    for (int j = 0; j < 4; ++j) lrow[j] = lrow[j] * sf[j] + rs[j];
    #pragma unroll
    for (int nf = 0; nf < 4; ++nf)
      #pragma unroll
      for (int j = 0; j < 4; ++j) oacc[nf][j] *= sf[j];

    #pragma unroll
    for (int nf = 0; nf < 4; ++nf)
      #pragma unroll
      for (int j = 0; j < 4; ++j)
        sP[SW(wv * 1024 + (lb * 4 + j) * 64 + nf * 16 + la)] = (bf16_t)sacc[nf][j];

    __builtin_amdgcn_s_setprio(1);
    #pragma unroll
    for (int ks = 0; ks < 2; ++ks) {
      const bf16x8 pa = *(const bf16x8*)&sP[SW(wv * 1024 + la * 64 + ks * 32 + lb * 8)];
      #pragma unroll
      for (int nf = 0; nf < 4; ++nf) {
        const bf16x8 vb2 = *(const bf16x8*)&sVt[SW((nf * 16 + la) * 64 + ks * 32 + lb * 8)];
        oacc[nf] = __builtin_amdgcn_mfma_f32_16x16x32_bf16(pa, vb2, oacc[nf], 0, 0, 0);
      }
    }
    __builtin_amdgcn_s_setprio(0);
  }

  #pragma unroll
  for (int nf = 0; nf < 4; ++nf) {
    const int d = nf * 16 + la;
    #pragma unroll
    for (int j = 0; j < 4; ++j) {
      const int s = qb * 64 + wv * 16 + lb * 4 + j;
      const float val = oacc[nf][j] / lrow[j];
      O[(((size_t)b * 2048 + s) * 16 + h) * 64 + d] = (bf16_t)val;
    }
  }
}

extern "C" void kernel_launch(void* const* d_in, const int* in_sizes, int n_in,
                              void* d_out, int out_size, void* d_ws, size_t ws_size,
                              hipStream_t stream)
{
  const float* x      = (const float*)d_in[0];
  const int*   tokpos = (const int*)d_in[1];
  const float* qw     = (const float*)d_in[2];
  const float* kw     = (const float*)d_in[3];
  const float* vw     = (const float*)d_in[4];
  const float* ow     = (const float*)d_in[5];
  float* out = (float*)d_out;

  const size_t E  = (size_t)4 * 16 * 2048 * 64;  // 8388608 elems per activation
  const size_t W1 = (size_t)1024 * 1024;         // weight elems
  bf16_t* base = (bf16_t*)d_ws;
  bf16_t* Qhi = base;
  bf16_t* Qlo = base + E;
  bf16_t* Khi = base + 2 * E;
  bf16_t* Klo = base + 3 * E;
  bf16_t* Vt  = base + 4 * E;        // [B,H,D,S]
  bf16_t* Xh  = base + 5 * E;
  bf16_t* Xl  = base + 6 * E;
  bf16_t* QWh = base + 7 * E;
  bf16_t* QWl = QWh + W1;
  bf16_t* KWh = QWh + 2 * W1;
  bf16_t* KWl = QWh + 3 * W1;
  bf16_t* VWh = QWh + 4 * W1;
  bf16_t* OWh = QWh + 5 * W1;
  float*  ropeT = (float*)(QWh + 6 * W1);        // 2048*64 floats
  bf16_t* O = Xh;                                 // alias: X dead before attn

  RopeTab tab;
  for (int i = 0; i < 32; ++i)
    tab.inv[i] = (float)pow(10000.0, -(double)i / 32.0);

  // pre-passes
  split_k<true ><<<8192, 256, 0, stream>>>(x,  Xh,  Xl);
  split_k<true ><<<1024, 256, 0, stream>>>(qw, QWh, QWl);
  split_k<true ><<<1024, 256, 0, stream>>>(kw, KWh, KWl);
  split_k<false><<<1024, 256, 0, stream>>>(vw, VWh, nullptr);
  split_k<false><<<1024, 256, 0, stream>>>(ow, OWh, nullptr);
  rope_tab_k<<<256, 256, 0, stream>>>(tab, ropeT);

  // Q and K projections (merged, z selects weights), RoPE fused
  gemm_k<0><<<dim3(64, 8, 2), 256, 0, stream>>>(
      Xh, Xl, QWh, QWl, KWh, KWl, tokpos, ropeT, Qhi, Qlo, Khi, Klo, nullptr);
  // V projection -> V^T [B,H,D,S]
  gemm_k<1><<<dim3(64, 8, 1), 256, 0, stream>>>(
      Xh, nullptr, VWh, nullptr, VWh, nullptr, tokpos, ropeT,
      Vt, nullptr, nullptr, nullptr, nullptr);
  // attention
  attn_kernel<<<dim3(32, 64), 256, 0, stream>>>(Qhi, Qlo, Khi, Klo, Vt, O);
  // output projection -> fp32 d_out
  gemm_k<2><<<dim3(64, 8, 1), 256, 0, stream>>>(
      O, nullptr, OWh, nullptr, OWh, nullptr, tokpos, ropeT,
      nullptr, nullptr, nullptr, nullptr, out);
}

// Round 4
// 383.957 us; speedup vs baseline: 2.8732x; 1.2408x over previous
//
#include <hip/hip_runtime.h>
#include <cmath>

// MHA fused forward, MI355X gfx950.
// R3: attn rewritten in swapped-operand form:
//   - QK^T computed as mfma(K,Q) -> q is lane-local -> scalar (m,l) per lane,
//     2-round shfl row-reduce (was 4 rows/lane, 4 rounds)
//   - PV computed as mfma(Vt,P) -> O^T frag; packed b64 P-stores + O-stores
//   - K/V tiles staged with global_load_lds w=16 (linear LDS dest,
//     inverse-swizzled global source, swizzled ds_read; rule #21)
// GEMMs / pre-passes unchanged from R2.

typedef __bf16 bf16_t;
typedef __bf16 bf16x4 __attribute__((ext_vector_type(4)));
typedef __bf16 bf16x8 __attribute__((ext_vector_type(8)));
typedef float f32x2 __attribute__((ext_vector_type(2)));
typedef float f32x4 __attribute__((ext_vector_type(4)));
typedef unsigned int u32;
typedef const __attribute__((address_space(1))) u32* gaddr_t;
typedef __attribute__((address_space(3))) u32* saddr_t;

struct RopeTab { float inv[32]; };

// ---------------- pre-pass: fp32 -> bf16 hi (+lo) ----------------
template<bool LO>
__global__ __launch_bounds__(256) void split_k(const float* __restrict__ in,
                                               bf16_t* __restrict__ hi,
                                               bf16_t* __restrict__ lo)
{
  const int i = blockIdx.x * 256 + threadIdx.x;
  const f32x4 u = *(const f32x4*)(in + (size_t)i * 4);
  bf16x4 h, l;
  #pragma unroll
  for (int j = 0; j < 4; ++j) {
    const bf16_t hb = (bf16_t)u[j];
    h[j] = hb;
    if (LO) l[j] = (bf16_t)(u[j] - (float)hb);
  }
  *(bf16x4*)(hi + (size_t)i * 4) = h;
  if (LO) *(bf16x4*)(lo + (size_t)i * 4) = l;
}

// ---------------- pre-pass: RoPE cos/sin table [pos][32 pairs] ----------------
__global__ __launch_bounds__(256) void rope_tab_k(RopeTab tab, float* __restrict__ T)
{
  const int i = blockIdx.x * 256 + threadIdx.x;   // 2048*32 entries
  const int p = i >> 5, d2 = i & 31;
  float sn, cs;
  sincosf((float)p * tab.inv[d2], &sn, &cs);
  T[(size_t)i * 2]     = cs;
  T[(size_t)i * 2 + 1] = sn;
}

// ---------------- GEMM (B^T): out[m,n] = sum_k A[m,k] * W[n,k] ----------------
// MODE 0: A = Xh/Xl, W = Wh/Wl (z selects q/k weights), K_eff=3072 (3 segments:
//         hh, hl, lh). Epilogue: RoPE via table -> hi/lo bf16 out [B,H,S,D].
// MODE 1: plain bf16 K=1024, out bf16 transposed [B,H,D,S] (packed 8B stores).
// MODE 2: plain bf16 K=1024, out fp32 [M,N].
template<int MODE>
__global__ __launch_bounds__(256) void gemm_k(
    const bf16_t* __restrict__ Agh, const bf16_t* __restrict__ Agl,
    const bf16_t* __restrict__ W0h, const bf16_t* __restrict__ W0l,
    const bf16_t* __restrict__ W1h, const bf16_t* __restrict__ W1l,
    const int* __restrict__ tokpos, const float* __restrict__ ropeT,
    bf16_t* __restrict__ Oq_h, bf16_t* __restrict__ Oq_l,
    bf16_t* __restrict__ Ok_h, bf16_t* __restrict__ Ok_l,
    float* __restrict__ Of)
{
  __shared__ __align__(16) bf16_t sA[128 * 64];
  __shared__ __align__(16) bf16_t sB[128 * 64];

  const int tid = threadIdx.x;
  const int lane = tid & 63, wv = tid >> 6;
  const int wr = wv >> 1, wc = wv & 1;
  const int la = lane & 15, lb = lane >> 4;
  const int row0 = blockIdx.x * 128, col0 = blockIdx.y * 128;
  const int z = blockIdx.z;

  const bf16_t* Wh = z ? W1h : W0h;
  const bf16_t* Wl = z ? W1l : W0l;

  // staging geometry: wave wv covers tile rows [wv*32, wv*32+32)
  const int srow = wv * 32 + (lane >> 3);   // + i*8
  const int schk = lane & 7;                // physical 16B chunk within row

  f32x4 acc[4][4] = {};

  const int NSEG = (MODE == 0) ? 3 : 1;
  for (int seg = 0; seg < NSEG; ++seg) {
    const bf16_t* Ap = (MODE == 0 && seg == 2) ? Agl : Agh;
    const bf16_t* Wp = (MODE == 0 && seg == 1) ? Wl  : Wh;
    for (int k0 = 0; k0 < 1024; k0 += 64) {
      __syncthreads();
      #pragma unroll
      for (int i = 0; i < 4; ++i) {
        const int r = srow + i * 8;
        const int cs_ = ((schk ^ (r & 7)) * 8);          // inverse-swizzled source col
        __builtin_amdgcn_global_load_lds(
            (gaddr_t)(Ap + (size_t)(row0 + r) * 1024 + k0 + cs_),
            (saddr_t)(sA + wv * 2048 + i * 512), 16, 0, 0);
        __builtin_amdgcn_global_load_lds(
            (gaddr_t)(Wp + (size_t)(col0 + r) * 1024 + k0 + cs_),
            (saddr_t)(sB + wv * 2048 + i * 512), 16, 0, 0);
      }
      __syncthreads();

      #pragma unroll
      for (int ks = 0; ks < 2; ++ks) {
        bf16x8 af[4];
        #pragma unroll
        for (int m = 0; m < 4; ++m) {
          const int r = wr * 64 + m * 16 + la;
          af[m] = *(const bf16x8*)&sA[r * 64 + (((ks * 4 + lb) ^ (la & 7)) * 8)];
        }
        #pragma unroll
        for (int n = 0; n < 4; ++n) {
          const int r = wc * 64 + n * 16 + la;
          const bf16x8 bfr = *(const bf16x8*)&sB[r * 64 + (((ks * 4 + lb) ^ (la & 7)) * 8)];
          #pragma unroll
          for (int m = 0; m < 4; ++m)
            acc[m][n] = __builtin_amdgcn_mfma_f32_16x16x32_bf16(af[m], bfr, acc[m][n], 0, 0, 0);
        }
      }
    }
  }

  // ---- epilogue ----
  #pragma unroll
  for (int n = 0; n < 4; ++n) {
    const int gn = col0 + wc * 64 + n * 16 + la;
    #pragma unroll
    for (int m = 0; m < 4; ++m) {
      const int gm0 = row0 + wr * 64 + m * 16 + lb * 4;
      if (MODE == 2) {
        #pragma unroll
        for (int j = 0; j < 4; ++j)
          Of[(size_t)(gm0 + j) * 1024 + gn] = acc[m][n][j];
      } else if (MODE == 1) {
        const int b = gm0 >> 11, s0 = gm0 & 2047;
        const int h = gn >> 6, d = gn & 63;
        bf16x4 v;
        #pragma unroll
        for (int j = 0; j < 4; ++j) v[j] = (bf16_t)acc[m][n][j];
        *(bf16x4*)&Oq_h[(((size_t)b * 16 + h) * 64 + d) * 2048 + s0] = v;
      } else {
        const int d = gn & 63, h = gn >> 6;
        const bool odd = d & 1;
        bf16_t* Oh = z ? Ok_h : Oq_h;
        bf16_t* Ol = z ? Ok_l : Oq_l;
        #pragma unroll
        for (int j = 0; j < 4; ++j) {
          const int gm = gm0 + j;
          const float t = acc[m][n][j];
          const float other = __shfl_xor(t, 1, 64);   // partner column d^1
          const int pos = tokpos[gm];
          const f32x2 cs2 = *(const f32x2*)&ropeT[((size_t)pos << 6) + ((d >> 1) << 1)];
          const float r = odd ? (other * cs2[1] + t * cs2[0])
                              : (t * cs2[0] - other * cs2[1]);
          const bf16_t hb = (bf16_t)r;
          const int b = gm >> 11, s = gm & 2047;
          const size_t oi = (((size_t)b * 16 + h) * 2048 + s) * 64 + d;
          Oh[oi] = hb;
          Ol[oi] = (bf16_t)(r - (float)hb);
        }
      }
    }
  }
}

// XOR swizzle for 64-elem-wide bf16 LDS tiles (row = 128B).
__device__ __forceinline__ int SW(int e) { return e ^ (((e >> 6) & 7) << 3); }

// Flash attention, causal, split-bf16 QK^T, swapped operands.
// Grid (S/64, B*H), 4 waves/block. V input pre-transposed [B,H,D,S].
// Per lane: q = qb*64 + wv*16 + la (FIXED). S^T frag: kv = nf*16+lb*4+j.
// O^T frag: d = nf*16+lb*4+j.
__global__ __launch_bounds__(256) void attn_kernel(
    const bf16_t* __restrict__ Qhi, const bf16_t* __restrict__ Qlo,
    const bf16_t* __restrict__ Khi, const bf16_t* __restrict__ Klo,
    const bf16_t* __restrict__ Vt, bf16_t* __restrict__ O)
{
  __shared__ __align__(16) bf16_t sKh[64 * 64];
  __shared__ __align__(16) bf16_t sKl[64 * 64];
  __shared__ __align__(16) bf16_t sVt[64 * 64];   // [d][kv]
  __shared__ __align__(16) bf16_t sP[4 * 16 * 64]; // per-wave [q=la][kv], la-swizzled

  const int qb = (int)gridDim.x - 1 - (int)blockIdx.x;  // longest-first
  const int bh = blockIdx.y;
  const int b = bh >> 4, h = bh & 15;
  const size_t base = (size_t)bh * 2048 * 64;
  const bf16_t* Qh_ = Qhi + base;
  const bf16_t* Ql_ = Qlo + base;
  const bf16_t* Kh_ = Khi + base;
  const bf16_t* Kl_ = Klo + base;
  const bf16_t* Vt_ = Vt + base;    // [64 d][2048 s]

  const int tid = threadIdx.x, wv = tid >> 6, lane = tid & 63;
  const int la = lane & 15, lb = lane >> 4;

  const int q = qb * 64 + wv * 16 + la;   // this lane's q row (global)
  bf16x8 qh[2], ql[2];
  #pragma unroll
  for (int kf = 0; kf < 2; ++kf) {
    qh[kf] = *(const bf16x8*)&Qh_[(size_t)q * 64 + kf * 32 + lb * 8];
    ql[kf] = *(const bf16x8*)&Ql_[(size_t)q * 64 + kf * 32 + lb * 8];
  }

  f32x4 oacc[4] = {};       // oacc[nf][j] = O^T[d = nf*16+lb*4+j][q = la]
  float m = -1e30f, l = 0.f;
  const int psw = (la & 7) << 3;           // sP swizzle key (kv bits 3..5)

  for (int kvb = 0; kvb <= qb; ++kvb) {
    const int kv0 = kvb * 64;
    __syncthreads();
    // stage 24KB via global_load_lds: 8 chunks of 1KB per tensor, 2 per wave.
    // LDS dest linear; global source chunk inverse-swizzled (rule #21).
    #pragma unroll
    for (int i = 0; i < 2; ++i) {
      const int e0 = (i * 4 + wv) * 512;          // wave-uniform chunk base (elems)
      const int e = e0 + lane * 8;                // this lane's dest elem
      const int r = e >> 6;                       // tile row
      const int csw = ((e >> 3) & 7) ^ (r & 7);   // swizzled source 16B-chunk
      const int src = r * 64 + csw * 8;
      __builtin_amdgcn_global_load_lds((gaddr_t)(Kh_ + (size_t)kv0 * 64 + src),
                                       (saddr_t)(sKh + e0), 16, 0, 0);
      __builtin_amdgcn_global_load_lds((gaddr_t)(Kl_ + (size_t)kv0 * 64 + src),
                                       (saddr_t)(sKl + e0), 16, 0, 0);
      __builtin_amdgcn_global_load_lds((gaddr_t)(Vt_ + (size_t)r * 2048 + kv0 + csw * 8),
                                       (saddr_t)(sVt + e0), 16, 0, 0);
    }
    __syncthreads();

    // S^T = K Q^T (3-term split): sacc[nf][j] at kv = kv0+nf*16+lb*4+j, q = la
    f32x4 sacc[4] = {};
    __builtin_amdgcn_s_setprio(1);
    #pragma unroll
    for (int nf = 0; nf < 4; ++nf) {
      #pragma unroll
      for (int kf = 0; kf < 2; ++kf) {
        const int rr = SW((nf * 16 + la) * 64 + kf * 32 + lb * 8);
        const bf16x8 kh = *(const bf16x8*)&sKh[rr];
        const bf16x8 kl = *(const bf16x8*)&sKl[rr];
        sacc[nf] = __builtin_amdgcn_mfma_f32_16x16x32_bf16(kh, qh[kf], sacc[nf], 0, 0, 0);
        sacc[nf] = __builtin_amdgcn_mfma_f32_16x16x32_bf16(kl, qh[kf], sacc[nf], 0, 0, 0);
        sacc[nf] = __builtin_amdgcn_mfma_f32_16x16x32_bf16(kh, ql[kf], sacc[nf], 0, 0, 0);
      }
    }
    __builtin_amdgcn_s_setprio(0);

    // mask + scale
    if (kvb == qb) {
      #pragma unroll
      for (int nf = 0; nf < 4; ++nf)
        #pragma unroll
        for (int j = 0; j < 4; ++j) {
          const int kvi = kv0 + nf * 16 + lb * 4 + j;
          sacc[nf][j] = (kvi <= q) ? sacc[nf][j] * 0.125f : -1e30f;
        }
    } else {
      #pragma unroll
      for (int nf = 0; nf < 4; ++nf)
        #pragma unroll
        for (int j = 0; j < 4; ++j) sacc[nf][j] *= 0.125f;
    }

    // row softmax: in-lane 16, then combine lb groups (lanes ^16, ^32)
    float red = sacc[0][0];
    #pragma unroll
    for (int nf = 0; nf < 4; ++nf)
      #pragma unroll
      for (int j = 0; j < 4; ++j) red = fmaxf(red, sacc[nf][j]);
    red = fmaxf(red, __shfl_xor(red, 16, 64));
    red = fmaxf(red, __shfl_xor(red, 32, 64));

    const float mn = fmaxf(m, red);
    const float sf = __expf(m - mn);
    m = mn;
    float rs = 0.f;
    #pragma unroll
    for (int nf = 0; nf < 4; ++nf)
      #pragma unroll
      for (int j = 0; j < 4; ++j) {
        const float p = __expf(sacc[nf][j] - m);
        sacc[nf][j] = p;
        rs += p;
      }
    rs += __shfl_xor(rs, 16, 64);
    rs += __shfl_xor(rs, 32, 64);
    l = l * sf + rs;
    #pragma unroll
    for (int nf = 0; nf < 4; ++nf)
      #pragma unroll
      for (int j = 0; j < 4; ++j) oacc[nf][j] *= sf;

    // P -> LDS: packed b64 per nf (4 consecutive kv), la-keyed swizzle
    #pragma unroll
    for (int nf = 0; nf < 4; ++nf) {
      bf16x4 pv;
      #pragma unroll
      for (int j = 0; j < 4; ++j) pv[j] = (bf16_t)sacc[nf][j];
      *(bf16x4*)&sP[wv * 1024 + la * 64 + ((nf * 16 + lb * 4) ^ psw)] = pv;
    }

    // O^T += V^T P^T : mfma(A=Vt rows d, B=P rows q)
    __builtin_amdgcn_s_setprio(1);
    #pragma unroll
    for (int ks = 0; ks < 2; ++ks) {
      const bf16x8 pa = *(const bf16x8*)&sP[wv * 1024 + la * 64 + ((ks * 32 + lb * 8) ^ psw)];
      #pragma unroll
      for (int nf = 0; nf < 4; ++nf) {
        const bf16x8 vb2 = *(const bf16x8*)&sVt[SW((nf * 16 + la) * 64 + ks * 32 + lb * 8)];
        oacc[nf] = __builtin_amdgcn_mfma_f32_16x16x32_bf16(vb2, pa, oacc[nf], 0, 0, 0);
      }
    }
    __builtin_amdgcn_s_setprio(0);
  }

  // epilogue: O[b,s,h,d] bf16, packed b64 (4 consecutive d per nf)
  const float inv_l = 1.0f / l;
  const int s = q;
  #pragma unroll
  for (int nf = 0; nf < 4; ++nf) {
    bf16x4 ov;
    #pragma unroll
    for (int j = 0; j < 4; ++j) ov[j] = (bf16_t)(oacc[nf][j] * inv_l);
    const int d0 = nf * 16 + lb * 4;
    *(bf16x4*)&O[(((size_t)b * 2048 + s) * 16 + h) * 64 + d0] = ov;
  }
}

extern "C" void kernel_launch(void* const* d_in, const int* in_sizes, int n_in,
                              void* d_out, int out_size, void* d_ws, size_t ws_size,
                              hipStream_t stream)
{
  const float* x      = (const float*)d_in[0];
  const int*   tokpos = (const int*)d_in[1];
  const float* qw     = (const float*)d_in[2];
  const float* kw     = (const float*)d_in[3];
  const float* vw     = (const float*)d_in[4];
  const float* ow     = (const float*)d_in[5];
  float* out = (float*)d_out;

  const size_t E  = (size_t)4 * 16 * 2048 * 64;  // 8388608 elems per activation
  const size_t W1 = (size_t)1024 * 1024;         // weight elems
  bf16_t* base = (bf16_t*)d_ws;
  bf16_t* Qhi = base;
  bf16_t* Qlo = base + E;
  bf16_t* Khi = base + 2 * E;
  bf16_t* Klo = base + 3 * E;
  bf16_t* Vt  = base + 4 * E;        // [B,H,D,S]
  bf16_t* Xh  = base + 5 * E;
  bf16_t* Xl  = base + 6 * E;
  bf16_t* QWh = base + 7 * E;
  bf16_t* QWl = QWh + W1;
  bf16_t* KWh = QWh + 2 * W1;
  bf16_t* KWl = QWh + 3 * W1;
  bf16_t* VWh = QWh + 4 * W1;
  bf16_t* OWh = QWh + 5 * W1;
  float*  ropeT = (float*)(QWh + 6 * W1);        // 2048*64 floats
  bf16_t* O = Xh;                                 // alias: X dead before attn

  RopeTab tab;
  for (int i = 0; i < 32; ++i)
    tab.inv[i] = (float)pow(10000.0, -(double)i / 32.0);

  // pre-passes
  split_k<true ><<<8192, 256, 0, stream>>>(x,  Xh,  Xl);
  split_k<true ><<<1024, 256, 0, stream>>>(qw, QWh, QWl);
  split_k<true ><<<1024, 256, 0, stream>>>(kw, KWh, KWl);
  split_k<false><<<1024, 256, 0, stream>>>(vw, VWh, nullptr);
  split_k<false><<<1024, 256, 0, stream>>>(ow, OWh, nullptr);
  rope_tab_k<<<256, 256, 0, stream>>>(tab, ropeT);

  // Q and K projections (merged, z selects weights), RoPE fused
  gemm_k<0><<<dim3(64, 8, 2), 256, 0, stream>>>(
      Xh, Xl, QWh, QWl, KWh, KWl, tokpos, ropeT, Qhi, Qlo, Khi, Klo, nullptr);
  // V projection -> V^T [B,H,D,S]
  gemm_k<1><<<dim3(64, 8, 1), 256, 0, stream>>>(
      Xh, nullptr, VWh, nullptr, VWh, nullptr, tokpos, ropeT,
      Vt, nullptr, nullptr, nullptr, nullptr);
  // attention
  attn_kernel<<<dim3(32, 64), 256, 0, stream>>>(Qhi, Qlo, Khi, Klo, Vt, O);
  // output projection -> fp32 d_out
  gemm_k<2><<<dim3(64, 8, 1), 256, 0, stream>>>(
      O, nullptr, OWh, nullptr, OWh, nullptr, tokpos, ropeT,
      nullptr, nullptr, nullptr, nullptr, out);
}

// Round 5
// 314.155 us; speedup vs baseline: 3.5117x; 1.2222x over previous
//
#include <hip/hip_runtime.h>
#include <cmath>

// MHA fused forward, MI355X gfx950.
// R4: attn pipelined:
//   - QBLK=128, 8 waves/block (staging per q-row halved, MFMA density 2x)
//   - double-buffered K/V prefetch: issue next tile's global_load_lds BEFORE
//     computing current; one __syncthreads per tile drains it after compute
//   - XCD-aware block remap (each XCD owns an 8-head octet)
//   - defer-max rescale skip (THR=8)
// R3 kept: swapped-operand QK/PV, scalar (m,l), rule-#21 swizzled staging.
// GEMMs / pre-passes unchanged.

typedef __bf16 bf16_t;
typedef __bf16 bf16x4 __attribute__((ext_vector_type(4)));
typedef __bf16 bf16x8 __attribute__((ext_vector_type(8)));
typedef float f32x2 __attribute__((ext_vector_type(2)));
typedef float f32x4 __attribute__((ext_vector_type(4)));
typedef unsigned int u32;
typedef const __attribute__((address_space(1))) u32* gaddr_t;
typedef __attribute__((address_space(3))) u32* saddr_t;

struct RopeTab { float inv[32]; };

// ---------------- pre-pass: fp32 -> bf16 hi (+lo) ----------------
template<bool LO>
__global__ __launch_bounds__(256) void split_k(const float* __restrict__ in,
                                               bf16_t* __restrict__ hi,
                                               bf16_t* __restrict__ lo)
{
  const int i = blockIdx.x * 256 + threadIdx.x;
  const f32x4 u = *(const f32x4*)(in + (size_t)i * 4);
  bf16x4 h, l;
  #pragma unroll
  for (int j = 0; j < 4; ++j) {
    const bf16_t hb = (bf16_t)u[j];
    h[j] = hb;
    if (LO) l[j] = (bf16_t)(u[j] - (float)hb);
  }
  *(bf16x4*)(hi + (size_t)i * 4) = h;
  if (LO) *(bf16x4*)(lo + (size_t)i * 4) = l;
}

// ---------------- pre-pass: RoPE cos/sin table [pos][32 pairs] ----------------
__global__ __launch_bounds__(256) void rope_tab_k(RopeTab tab, float* __restrict__ T)
{
  const int i = blockIdx.x * 256 + threadIdx.x;   // 2048*32 entries
  const int p = i >> 5, d2 = i & 31;
  float sn, cs;
  sincosf((float)p * tab.inv[d2], &sn, &cs);
  T[(size_t)i * 2]     = cs;
  T[(size_t)i * 2 + 1] = sn;
}

// ---------------- GEMM (B^T): out[m,n] = sum_k A[m,k] * W[n,k] ----------------
// MODE 0: A = Xh/Xl, W = Wh/Wl (z selects q/k weights), K_eff=3072 (3 segments:
//         hh, hl, lh). Epilogue: RoPE via table -> hi/lo bf16 out [B,H,S,D].
// MODE 1: plain bf16 K=1024, out bf16 transposed [B,H,D,S] (packed 8B stores).
// MODE 2: plain bf16 K=1024, out fp32 [M,N].
template<int MODE>
__global__ __launch_bounds__(256) void gemm_k(
    const bf16_t* __restrict__ Agh, const bf16_t* __restrict__ Agl,
    const bf16_t* __restrict__ W0h, const bf16_t* __restrict__ W0l,
    const bf16_t* __restrict__ W1h, const bf16_t* __restrict__ W1l,
    const int* __restrict__ tokpos, const float* __restrict__ ropeT,
    bf16_t* __restrict__ Oq_h, bf16_t* __restrict__ Oq_l,
    bf16_t* __restrict__ Ok_h, bf16_t* __restrict__ Ok_l,
    float* __restrict__ Of)
{
  __shared__ __align__(16) bf16_t sA[128 * 64];
  __shared__ __align__(16) bf16_t sB[128 * 64];

  const int tid = threadIdx.x;
  const int lane = tid & 63, wv = tid >> 6;
  const int wr = wv >> 1, wc = wv & 1;
  const int la = lane & 15, lb = lane >> 4;
  const int row0 = blockIdx.x * 128, col0 = blockIdx.y * 128;
  const int z = blockIdx.z;

  const bf16_t* Wh = z ? W1h : W0h;
  const bf16_t* Wl = z ? W1l : W0l;

  // staging geometry: wave wv covers tile rows [wv*32, wv*32+32)
  const int srow = wv * 32 + (lane >> 3);   // + i*8
  const int schk = lane & 7;                // physical 16B chunk within row

  f32x4 acc[4][4] = {};

  const int NSEG = (MODE == 0) ? 3 : 1;
  for (int seg = 0; seg < NSEG; ++seg) {
    const bf16_t* Ap = (MODE == 0 && seg == 2) ? Agl : Agh;
    const bf16_t* Wp = (MODE == 0 && seg == 1) ? Wl  : Wh;
    for (int k0 = 0; k0 < 1024; k0 += 64) {
      __syncthreads();
      #pragma unroll
      for (int i = 0; i < 4; ++i) {
        const int r = srow + i * 8;
        const int cs_ = ((schk ^ (r & 7)) * 8);          // inverse-swizzled source col
        __builtin_amdgcn_global_load_lds(
            (gaddr_t)(Ap + (size_t)(row0 + r) * 1024 + k0 + cs_),
            (saddr_t)(sA + wv * 2048 + i * 512), 16, 0, 0);
        __builtin_amdgcn_global_load_lds(
            (gaddr_t)(Wp + (size_t)(col0 + r) * 1024 + k0 + cs_),
            (saddr_t)(sB + wv * 2048 + i * 512), 16, 0, 0);
      }
      __syncthreads();

      #pragma unroll
      for (int ks = 0; ks < 2; ++ks) {
        bf16x8 af[4];
        #pragma unroll
        for (int m = 0; m < 4; ++m) {
          const int r = wr * 64 + m * 16 + la;
          af[m] = *(const bf16x8*)&sA[r * 64 + (((ks * 4 + lb) ^ (la & 7)) * 8)];
        }
        #pragma unroll
        for (int n = 0; n < 4; ++n) {
          const int r = wc * 64 + n * 16 + la;
          const bf16x8 bfr = *(const bf16x8*)&sB[r * 64 + (((ks * 4 + lb) ^ (la & 7)) * 8)];
          #pragma unroll
          for (int m = 0; m < 4; ++m)
            acc[m][n] = __builtin_amdgcn_mfma_f32_16x16x32_bf16(af[m], bfr, acc[m][n], 0, 0, 0);
        }
      }
    }
  }

  // ---- epilogue ----
  #pragma unroll
  for (int n = 0; n < 4; ++n) {
    const int gn = col0 + wc * 64 + n * 16 + la;
    #pragma unroll
    for (int m = 0; m < 4; ++m) {
      const int gm0 = row0 + wr * 64 + m * 16 + lb * 4;
      if (MODE == 2) {
        #pragma unroll
        for (int j = 0; j < 4; ++j)
          Of[(size_t)(gm0 + j) * 1024 + gn] = acc[m][n][j];
      } else if (MODE == 1) {
        const int b = gm0 >> 11, s0 = gm0 & 2047;
        const int h = gn >> 6, d = gn & 63;
        bf16x4 v;
        #pragma unroll
        for (int j = 0; j < 4; ++j) v[j] = (bf16_t)acc[m][n][j];
        *(bf16x4*)&Oq_h[(((size_t)b * 16 + h) * 64 + d) * 2048 + s0] = v;
      } else {
        const int d = gn & 63, h = gn >> 6;
        const bool odd = d & 1;
        bf16_t* Oh = z ? Ok_h : Oq_h;
        bf16_t* Ol = z ? Ok_l : Oq_l;
        #pragma unroll
        for (int j = 0; j < 4; ++j) {
          const int gm = gm0 + j;
          const float t = acc[m][n][j];
          const float other = __shfl_xor(t, 1, 64);   // partner column d^1
          const int pos = tokpos[gm];
          const f32x2 cs2 = *(const f32x2*)&ropeT[((size_t)pos << 6) + ((d >> 1) << 1)];
          const float r = odd ? (other * cs2[1] + t * cs2[0])
                              : (t * cs2[0] - other * cs2[1]);
          const bf16_t hb = (bf16_t)r;
          const int b = gm >> 11, s = gm & 2047;
          const size_t oi = (((size_t)b * 16 + h) * 2048 + s) * 64 + d;
          Oh[oi] = hb;
          Ol[oi] = (bf16_t)(r - (float)hb);
        }
      }
    }
  }
}

// XOR swizzle for 64-elem-wide bf16 LDS tiles (row = 128B).
__device__ __forceinline__ int SW(int e) { return e ^ (((e >> 6) & 7) << 3); }

// Flash attention, causal, split-bf16 QK^T, swapped operands, pipelined.
// Grid 1024 blocks x 512 threads. QBLK=128 (8 waves x 16 q-rows), KVBLK=64.
// Double-buffered K/V staging: prefetch next tile before computing current.
__global__ __launch_bounds__(512, 4) void attn_kernel(
    const bf16_t* __restrict__ Qhi, const bf16_t* __restrict__ Qlo,
    const bf16_t* __restrict__ Khi, const bf16_t* __restrict__ Klo,
    const bf16_t* __restrict__ Vt, bf16_t* __restrict__ O)
{
  // [buf][ Kh(4096) | Kl(4096) | Vt(4096) ]
  __shared__ __align__(16) bf16_t sKV[2][3 * 4096];
  __shared__ __align__(16) bf16_t sP[8 * 1024];   // per-wave [q=la][kv], la-swizzled

  // XCD-aware remap: linear%8 selects XCD-octet of heads; longest-first qb.
  const int linear = (int)blockIdx.y * (int)gridDim.x + (int)blockIdx.x;
  const int xcd = linear & 7;
  const int pos = linear >> 3;            // 0..127
  const int bh  = xcd * 8 + (pos >> 4);   // [0,64)
  const int qb  = 15 - (pos & 15);        // longest-first
  const int b = bh >> 4, h = bh & 15;

  const size_t base = (size_t)bh * 2048 * 64;
  const bf16_t* Qh_ = Qhi + base;
  const bf16_t* Ql_ = Qlo + base;
  const bf16_t* Kh_ = Khi + base;
  const bf16_t* Kl_ = Klo + base;
  const bf16_t* Vt_ = Vt + base;    // [64 d][2048 s]

  const int tid = threadIdx.x, wv = tid >> 6, lane = tid & 63;
  const int la = lane & 15, lb = lane >> 4;

  const int q = qb * 128 + wv * 16 + la;   // this lane's q row (global)
  bf16x8 qh[2], ql[2];
  #pragma unroll
  for (int kf = 0; kf < 2; ++kf) {
    qh[kf] = *(const bf16x8*)&Qh_[(size_t)q * 64 + kf * 32 + lb * 8];
    ql[kf] = *(const bf16x8*)&Ql_[(size_t)q * 64 + kf * 32 + lb * 8];
  }

  // staging geometry (per thread, 3 x 16B): covers 24KB over 512 threads
  const int sr   = wv * 8 + (lane >> 3);        // tile row 0..63
  const int scsw = (lane & 7) ^ (sr & 7);       // inverse-swizzled 16B chunk
  const int ssrc = sr * 64 + scsw * 8;          // K source elem offset in tile
  const int se0  = wv * 512;                    // wave-uniform LDS chunk base

  f32x4 oacc[4] = {};       // oacc[nf][j] = O^T[d = nf*16+lb*4+j][q = la]
  float m = -1e30f, l = 0.f;
  const int psw = (la & 7) << 3;           // sP swizzle key (kv bits 3..5)

  const int nt = 2 * qb + 2;               // kv tiles (KVBLK=64)

  // prologue: stage tile 0 into buf 0
  {
    bf16_t* dst = &sKV[0][0];
    __builtin_amdgcn_global_load_lds((gaddr_t)(Kh_ + ssrc), (saddr_t)(dst + se0), 16, 0, 0);
    __builtin_amdgcn_global_load_lds((gaddr_t)(Kl_ + ssrc), (saddr_t)(dst + 4096 + se0), 16, 0, 0);
    __builtin_amdgcn_global_load_lds((gaddr_t)(Vt_ + (size_t)sr * 2048 + scsw * 8),
                                     (saddr_t)(dst + 8192 + se0), 16, 0, 0);
  }
  __syncthreads();

  int cur = 0;
  for (int kvb = 0; kvb < nt; ++kvb) {
    const int kv0 = kvb * 64;

    // prefetch next tile into the other buffer (drained by the syncthreads
    // at the END of this iteration -> latency hidden under compute below)
    if (kvb + 1 < nt) {
      const int nkv0 = kv0 + 64;
      bf16_t* dst = &sKV[cur ^ 1][0];
      __builtin_amdgcn_global_load_lds((gaddr_t)(Kh_ + (size_t)nkv0 * 64 + ssrc),
                                       (saddr_t)(dst + se0), 16, 0, 0);
      __builtin_amdgcn_global_load_lds((gaddr_t)(Kl_ + (size_t)nkv0 * 64 + ssrc),
                                       (saddr_t)(dst + 4096 + se0), 16, 0, 0);
      __builtin_amdgcn_global_load_lds((gaddr_t)(Vt_ + (size_t)sr * 2048 + nkv0 + scsw * 8),
                                       (saddr_t)(dst + 8192 + se0), 16, 0, 0);
    }

    const bf16_t* sKh = &sKV[cur][0];
    const bf16_t* sKl = sKh + 4096;
    const bf16_t* sVt = sKh + 8192;

    // S^T = K Q^T (3-term split): sacc[nf][j] at kv = kv0+nf*16+lb*4+j, q fixed
    f32x4 sacc[4] = {};
    __builtin_amdgcn_s_setprio(1);
    #pragma unroll
    for (int nf = 0; nf < 4; ++nf) {
      #pragma unroll
      for (int kf = 0; kf < 2; ++kf) {
        const int rr = SW((nf * 16 + la) * 64 + kf * 32 + lb * 8);
        const bf16x8 kh = *(const bf16x8*)&sKh[rr];
        const bf16x8 kl = *(const bf16x8*)&sKl[rr];
        sacc[nf] = __builtin_amdgcn_mfma_f32_16x16x32_bf16(kh, qh[kf], sacc[nf], 0, 0, 0);
        sacc[nf] = __builtin_amdgcn_mfma_f32_16x16x32_bf16(kl, qh[kf], sacc[nf], 0, 0, 0);
        sacc[nf] = __builtin_amdgcn_mfma_f32_16x16x32_bf16(kh, ql[kf], sacc[nf], 0, 0, 0);
      }
    }
    __builtin_amdgcn_s_setprio(0);

    // mask + scale (mask only possibly-diagonal tiles: kvb >= 2*qb)
    if (kvb >= 2 * qb) {
      #pragma unroll
      for (int nf = 0; nf < 4; ++nf)
        #pragma unroll
        for (int j = 0; j < 4; ++j) {
          const int kvi = kv0 + nf * 16 + lb * 4 + j;
          sacc[nf][j] = (kvi <= q) ? sacc[nf][j] * 0.125f : -1e30f;
        }
    } else {
      #pragma unroll
      for (int nf = 0; nf < 4; ++nf)
        #pragma unroll
        for (int j = 0; j < 4; ++j) sacc[nf][j] *= 0.125f;
    }

    // row softmax: in-lane 16, then combine lb groups (lanes ^16, ^32)
    float red = sacc[0][0];
    #pragma unroll
    for (int nf = 0; nf < 4; ++nf)
      #pragma unroll
      for (int j = 0; j < 4; ++j) red = fmaxf(red, sacc[nf][j]);
    red = fmaxf(red, __shfl_xor(red, 16, 64));
    red = fmaxf(red, __shfl_xor(red, 32, 64));

    // defer-max (T13): only rescale when the max grew by more than THR=8
    const float mn = fmaxf(m, red);
    if (!__all(mn - m <= 8.0f)) {
      const float sf = __expf(m - mn);
      m = mn;
      l *= sf;
      #pragma unroll
      for (int nf = 0; nf < 4; ++nf)
        #pragma unroll
        for (int j = 0; j < 4; ++j) oacc[nf][j] *= sf;
    }

    float rs = 0.f;
    #pragma unroll
    for (int nf = 0; nf < 4; ++nf)
      #pragma unroll
      for (int j = 0; j < 4; ++j) {
        const float p = __expf(sacc[nf][j] - m);
        sacc[nf][j] = p;
        rs += p;
      }
    rs += __shfl_xor(rs, 16, 64);
    rs += __shfl_xor(rs, 32, 64);
    l += rs;

    // P -> LDS: packed b64 per nf (4 consecutive kv), la-keyed swizzle
    #pragma unroll
    for (int nf = 0; nf < 4; ++nf) {
      bf16x4 pv;
      #pragma unroll
      for (int j = 0; j < 4; ++j) pv[j] = (bf16_t)sacc[nf][j];
      *(bf16x4*)&sP[wv * 1024 + la * 64 + ((nf * 16 + lb * 4) ^ psw)] = pv;
    }

    // O^T += V^T P^T : mfma(A=Vt rows d, B=P rows q)
    __builtin_amdgcn_s_setprio(1);
    #pragma unroll
    for (int ks = 0; ks < 2; ++ks) {
      const bf16x8 pa = *(const bf16x8*)&sP[wv * 1024 + la * 64 + ((ks * 32 + lb * 8) ^ psw)];
      #pragma unroll
      for (int nf = 0; nf < 4; ++nf) {
        const bf16x8 vb2 = *(const bf16x8*)&sVt[SW((nf * 16 + la) * 64 + ks * 32 + lb * 8)];
        oacc[nf] = __builtin_amdgcn_mfma_f32_16x16x32_bf16(vb2, pa, oacc[nf], 0, 0, 0);
      }
    }
    __builtin_amdgcn_s_setprio(0);

    __syncthreads();   // drains prefetch (vmcnt) + guards buffer overwrite
    cur ^= 1;
  }

  // epilogue: O[b,s,h,d] bf16, packed b64 (4 consecutive d per nf)
  const float inv_l = 1.0f / l;
  const int s = q;
  #pragma unroll
  for (int nf = 0; nf < 4; ++nf) {
    bf16x4 ov;
    #pragma unroll
    for (int j = 0; j < 4; ++j) ov[j] = (bf16_t)(oacc[nf][j] * inv_l);
    const int d0 = nf * 16 + lb * 4;
    *(bf16x4*)&O[(((size_t)b * 2048 + s) * 16 + h) * 64 + d0] = ov;
  }
}

extern "C" void kernel_launch(void* const* d_in, const int* in_sizes, int n_in,
                              void* d_out, int out_size, void* d_ws, size_t ws_size,
                              hipStream_t stream)
{
  const float* x      = (const float*)d_in[0];
  const int*   tokpos = (const int*)d_in[1];
  const float* qw     = (const float*)d_in[2];
  const float* kw     = (const float*)d_in[3];
  const float* vw     = (const float*)d_in[4];
  const float* ow     = (const float*)d_in[5];
  float* out = (float*)d_out;

  const size_t E  = (size_t)4 * 16 * 2048 * 64;  // 8388608 elems per activation
  const size_t W1 = (size_t)1024 * 1024;         // weight elems
  bf16_t* base = (bf16_t*)d_ws;
  bf16_t* Qhi = base;
  bf16_t* Qlo = base + E;
  bf16_t* Khi = base + 2 * E;
  bf16_t* Klo = base + 3 * E;
  bf16_t* Vt  = base + 4 * E;        // [B,H,D,S]
  bf16_t* Xh  = base + 5 * E;
  bf16_t* Xl  = base + 6 * E;
  bf16_t* QWh = base + 7 * E;
  bf16_t* QWl = QWh + W1;
  bf16_t* KWh = QWh + 2 * W1;
  bf16_t* KWl = QWh + 3 * W1;
  bf16_t* VWh = QWh + 4 * W1;
  bf16_t* OWh = QWh + 5 * W1;
  float*  ropeT = (float*)(QWh + 6 * W1);        // 2048*64 floats
  bf16_t* O = Xh;                                 // alias: X dead before attn

  RopeTab tab;
  for (int i = 0; i < 32; ++i)
    tab.inv[i] = (float)pow(10000.0, -(double)i / 32.0);

  // pre-passes
  split_k<true ><<<8192, 256, 0, stream>>>(x,  Xh,  Xl);
  split_k<true ><<<1024, 256, 0, stream>>>(qw, QWh, QWl);
  split_k<true ><<<1024, 256, 0, stream>>>(kw, KWh, KWl);
  split_k<false><<<1024, 256, 0, stream>>>(vw, VWh, nullptr);
  split_k<false><<<1024, 256, 0, stream>>>(ow, OWh, nullptr);
  rope_tab_k<<<256, 256, 0, stream>>>(tab, ropeT);

  // Q and K projections (merged, z selects weights), RoPE fused
  gemm_k<0><<<dim3(64, 8, 2), 256, 0, stream>>>(
      Xh, Xl, QWh, QWl, KWh, KWl, tokpos, ropeT, Qhi, Qlo, Khi, Klo, nullptr);
  // V projection -> V^T [B,H,D,S]
  gemm_k<1><<<dim3(64, 8, 1), 256, 0, stream>>>(
      Xh, nullptr, VWh, nullptr, VWh, nullptr, tokpos, ropeT,
      Vt, nullptr, nullptr, nullptr, nullptr);
  // attention (1024 blocks x 512 threads, XCD-remapped inside)
  attn_kernel<<<dim3(16, 64), 512, 0, stream>>>(Qhi, Qlo, Khi, Klo, Vt, O);
  // output projection -> fp32 d_out
  gemm_k<2><<<dim3(64, 8, 1), 256, 0, stream>>>(
      O, nullptr, OWh, nullptr, OWh, nullptr, tokpos, ropeT,
      nullptr, nullptr, nullptr, nullptr, out);
}